// Round 17
// baseline (2312.348 us; speedup 1.0000x reference)
//
#include <hip/hip_runtime.h>

// ST-GCN classifier forward. Round 17: r16 (best, 2.000 ms) with ONE change:
// conv k-loop uses r13's NAMED ping-pong depth-2 weight prefetch (aA/aB,
// explicit even/odd pair loop — no indexed arrays) at the PROVEN BN=128
// tiling. De-confounds r13's regression (which was the BN=256 LDS cost).

#define NN 62
#define KK 9

typedef short s16x8 __attribute__((ext_vector_type(8)));
typedef float f32x4 __attribute__((ext_vector_type(4)));

__device__ __forceinline__ unsigned short f2bf(float f) {
  unsigned u = __builtin_bit_cast(unsigned, f);
  u += 0x7FFF + ((u >> 16) & 1);
  return (unsigned short)(u >> 16);
}
__device__ __forceinline__ float bf2f(unsigned short u) {
  unsigned v = ((unsigned)u) << 16;
  return __builtin_bit_cast(float, v);
}
__device__ __forceinline__ ushort4 pack4(float4 a) {
  return (ushort4){f2bf(a.x), f2bf(a.y), f2bf(a.z), f2bf(a.w)};
}

// ---------------- prep: gcn-normalized adjacency + adj passthrough ----------
__global__ __launch_bounds__(256) void k_prep(const float* __restrict__ adj,
                                              float* __restrict__ a_norm,
                                              float* __restrict__ out_adj) {
  __shared__ float dinv[NN];
  int tid = threadIdx.x;
  if (tid < NN) {
    float s = 1.0f;
    for (int n = 0; n < NN; n++) s += adj[tid * NN + n];
    dinv[tid] = (s > 0.f) ? rsqrtf(fmaxf(s, 1e-5f)) : 0.f;
  }
  __syncthreads();
  for (int idx = tid; idx < NN * NN; idx += 256) {
    int m = idx / NN, n = idx - m * NN;
    float ah = adj[idx] + ((m == n) ? 1.f : 0.f);
    a_norm[idx] = dinv[m] * ah * dinv[n];
    out_adj[idx] = adj[idx];
  }
}

// ------------- device helpers for weight layout transforms ------------------
__device__ __forceinline__ void wt_fill(const float* __restrict__ wc,
                                        unsigned short* __restrict__ wf, int C, int idx) {
  int total = KK * C * C;
  if (idx >= total) return;
  int nCB = C / 32;
  int j = idx & 7;
  int l = (idx >> 3) & 63;
  int rest = idx >> 9;
  int cb = rest % nCB;
  int rest2 = rest / nCB;
  int ob = rest2 % (C / 16);
  int k = rest2 / (C / 16);
  int o = ob * 16 + (l & 15);
  int ci = cb * 32 + (l >> 4) * 8 + j;
  wf[idx] = f2bf(wc[((size_t)o * C + ci) * KK + k]);
}
__device__ __forceinline__ void wg_fill(const float* __restrict__ gw,
                                        unsigned short* __restrict__ wgf,
                                        int CIN, int COUT, int KPAD, int idx) {
  int total = (COUT / 16) * (KPAD / 32) * 512;
  if (idx >= total) return;
  int j = idx & 7;
  int l = (idx >> 3) & 63;
  int rest = idx >> 9;
  int cb = rest % (KPAD / 32);
  int ob = rest / (KPAD / 32);
  int o = ob * 16 + (l & 15);
  int f = cb * 32 + (l >> 4) * 8 + j;
  wgf[idx] = (f < CIN) ? f2bf(gw[(size_t)f * COUT + o]) : (unsigned short)0;
}
__device__ __forceinline__ void wr_fill(const float* __restrict__ wr,
                                        unsigned short* __restrict__ wrf,
                                        int CIN, int COUT, int KPAD, int idx) {
  int total = (COUT / 16) * (KPAD / 32) * 512;
  if (idx >= total) return;
  int j = idx & 7;
  int l = (idx >> 3) & 63;
  int rest = idx >> 9;
  int cb = rest % (KPAD / 32);
  int ob = rest / (KPAD / 32);
  int o = ob * 16 + (l & 15);
  int f = cb * 32 + (l >> 4) * 8 + j;
  wrf[idx] = (f < CIN) ? f2bf(wr[(size_t)o * CIN + f]) : (unsigned short)0;
}

// ------------- unified one-launch weight prep (segment = blockIdx.y) --------
__global__ __launch_bounds__(256) void k_wall(
    const float* __restrict__ a_norm, unsigned short* __restrict__ anf,
    const float* __restrict__ cw0, unsigned short* __restrict__ wk0,
    const float* __restrict__ cw1, unsigned short* __restrict__ wk1,
    const float* __restrict__ cw2, unsigned short* __restrict__ wk2,
    const float* __restrict__ gw0, unsigned short* __restrict__ wg0f,
    const float* __restrict__ gw1, unsigned short* __restrict__ wg1f,
    const float* __restrict__ gw2, unsigned short* __restrict__ wg2f,
    const float* __restrict__ rw0, unsigned short* __restrict__ wr0f,
    const float* __restrict__ rw1, unsigned short* __restrict__ wr1f,
    const float* __restrict__ rw2, unsigned short* __restrict__ wr2f) {
  int idx = blockIdx.x * 256 + threadIdx.x;
  switch (blockIdx.y) {
    case 0: {
      if (idx < 4096) {
        int j = idx & 7;
        int l = (idx >> 3) & 63;
        int rest = idx >> 9;
        int cb = rest & 1;
        int ob = rest >> 1;
        int m = ob * 16 + (l & 15);
        int n = cb * 32 + (l >> 4) * 8 + j;
        anf[idx] = (m < NN && n < NN) ? f2bf(a_norm[m * NN + n]) : (unsigned short)0;
      }
      break;
    }
    case 1: wt_fill(cw0, wk0, 32, idx); break;
    case 2: wt_fill(cw1, wk1, 64, idx); break;
    case 3: wt_fill(cw2, wk2, 128, idx); break;
    case 4: wg_fill(gw0, wg0f, 5, 32, 32, idx); break;
    case 5: wg_fill(gw1, wg1f, 32, 64, 32, idx); break;
    case 6: wg_fill(gw2, wg2f, 64, 128, 64, idx); break;
    case 7: wr_fill(rw0, wr0f, 5, 32, 32, idx); break;
    case 8: wr_fill(rw1, wr1f, 32, 64, 32, idx); break;
    case 9: wr_fill(rw2, wr2f, 64, 128, 64, idx); break;
  }
}

// ---------------- x cast: (b0+bl, n, t, f=5) fp32 -> [bl][f][n][t] bf16 -----
__global__ __launch_bounds__(256) void k_xcast(const float* __restrict__ x,
                                               unsigned short* __restrict__ xb, int b0) {
  constexpr int TT2 = 256, TIN = 1024, CIN = 5;
  __shared__ float xt[TT2 * CIN];
  int t0 = blockIdx.x * TT2, n = blockIdx.y, bl = blockIdx.z;
  int tid = threadIdx.x;
  const float* xp = x + ((size_t)((b0 + bl) * NN + n) * TIN + t0) * CIN;
  for (int i = tid; i < TT2 * CIN; i += 256) xt[i] = xp[i];
  __syncthreads();
  for (int i = tid; i < CIN * TT2; i += 256) {
    int f = i / TT2, tl = i - f * TT2;
    xb[((size_t)bl * CIN + f) * NN * TIN + (size_t)n * TIN + t0 + tl] = f2bf(xt[tl * CIN + f]);
  }
}

// ---------------- spatial A-mix as bf16 MFMA GEMM ---------------------------
template <int CIN, int TIN>
__global__ __launch_bounds__(256) void k_spatmma(const unsigned short* __restrict__ in,
                                                 const unsigned short* __restrict__ anf,
                                                 unsigned short* __restrict__ xs) {
  constexpr int BT = 256;
  constexpr int CP = 72;
  constexpr int BNP = BT + 8;
  constexpr int ZTSZ = BT * CP;
  constexpr int WLSZ = 4096;
  constexpr int OTSZ = 64 * BNP;
  constexpr int SH = (ZTSZ + WLSZ > OTSZ) ? ZTSZ + WLSZ : OTSZ;
  __shared__ unsigned short sh[SH];
  unsigned short* zt = sh;
  unsigned short* wl = sh + ZTSZ;

  int t0 = blockIdx.x * BT;
  int f = blockIdx.y;
  int bl = blockIdx.z;
  int tid = threadIdx.x;

  for (int i = tid * 4; i < WLSZ; i += 1024)
    *reinterpret_cast<ushort4*>(&wl[i]) = *reinterpret_cast<const ushort4*>(&anf[i]);

  const unsigned short* ib = in + ((size_t)bl * CIN + f) * (size_t)NN * TIN;
  for (int i = tid * 4; i < 64 * BT; i += 1024) {
    int n = i / BT, tl = i - n * BT;
    ushort4 u = {0, 0, 0, 0};
    if (n < NN) u = *reinterpret_cast<const ushort4*>(&ib[(size_t)n * TIN + t0 + tl]);
    unsigned short vv[4] = {u.x, u.y, u.z, u.w};
    int xo = ((tl >> 2) & 7) << 3;
#pragma unroll
    for (int j = 0; j < 4; j++) zt[(tl + j) * CP + (n ^ xo)] = vv[j];
  }
  __syncthreads();

  int w = tid >> 6;
  int lane = tid & 63;
  int lm = lane & 15, kh = lane >> 4;
  int col0 = w * 64;

  f32x4 acc[4][4];
#pragma unroll
  for (int mf = 0; mf < 4; mf++)
#pragma unroll
    for (int nf = 0; nf < 4; nf++) acc[mf][nf] = (f32x4){0.f, 0.f, 0.f, 0.f};

#pragma unroll
  for (int cb = 0; cb < 2; cb++) {
    s16x8 a[4], b[4];
#pragma unroll
    for (int mf = 0; mf < 4; mf++)
      a[mf] = *reinterpret_cast<const s16x8*>(&wl[(mf * 2 + cb) * 512 + lane * 8]);
#pragma unroll
    for (int nf = 0; nf < 4; nf++) {
      int col = col0 + nf * 16 + lm;
      int off = (cb * 32 + kh * 8) ^ (((col >> 2) & 7) << 3);
      b[nf] = *reinterpret_cast<const s16x8*>(&zt[col * CP + off]);
    }
#pragma unroll
    for (int mf = 0; mf < 4; mf++)
#pragma unroll
      for (int nf = 0; nf < 4; nf++)
        acc[mf][nf] = __builtin_amdgcn_mfma_f32_16x16x32_bf16(a[mf], b[nf], acc[mf][nf], 0, 0, 0);
  }

  __syncthreads();
  unsigned short* ot = sh;
#pragma unroll
  for (int mf = 0; mf < 4; mf++)
#pragma unroll
    for (int nf = 0; nf < 4; nf++) {
      int col = col0 + nf * 16 + lm;
#pragma unroll
      for (int rr = 0; rr < 4; rr++) {
        int m = mf * 16 + kh * 4 + rr;
        ot[m * BNP + col] = f2bf(acc[mf][nf][rr]);
      }
    }
  __syncthreads();
  for (int i = tid * 4; i < NN * BT; i += 1024) {
    int m = i / BT, col = i - m * BT;
    ushort4 v = *reinterpret_cast<const ushort4*>(&ot[m * BNP + col]);
    *reinterpret_cast<ushort4*>(&xs[(((size_t)bl * CIN + f) * NN + m) * TIN + t0 + col]) = v;
  }
}

// ---------------- channel mix as bf16 MFMA GEMM + fused stats ---------------
template <int CIN, int COUT, int TIN>
__global__ __launch_bounds__(256) void k_wmixmma(const unsigned short* __restrict__ xs,
                                                 const unsigned short* __restrict__ wgf,
                                                 unsigned short* __restrict__ y,
                                                 float* __restrict__ part) {
  constexpr int S = NN * TIN;
  constexpr int KPAD = (CIN <= 32) ? 32 : 64;
  constexpr int CP = KPAD + 8;
  constexpr int BN = (COUT >= 128) ? 128 : 256;
  constexpr int BNP = BN + 8;
  constexpr int WM = (COUT >= 64) ? 2 : 1;
  constexpr int WN = 4 / WM;
  constexpr int MF = COUT / (16 * WM);
  constexpr int NF = BN / (16 * WN);
  constexpr int XM = (KPAD == 32) ? 3 : 7;
  constexpr int ZTSZ = BN * CP;
  constexpr int WLSZ = COUT * KPAD;
  constexpr int OTSZ = COUT * BNP;
  constexpr int SH = (ZTSZ + WLSZ > OTSZ) ? ZTSZ + WLSZ : OTSZ;
  __shared__ unsigned short sh[SH];
  unsigned short* zt = sh;
  unsigned short* wl = sh + ZTSZ;

  int s0 = blockIdx.x * BN;
  int bl = blockIdx.y;
  int tid = threadIdx.x;

  for (int i = tid * 4; i < WLSZ; i += 1024)
    *reinterpret_cast<ushort4*>(&wl[i]) = *reinterpret_cast<const ushort4*>(&wgf[i]);

  const unsigned short* xb = xs + (size_t)bl * CIN * S;
  for (int i = tid * 4; i < KPAD * BN; i += 1024) {
    int f = i / BN, sl = i - (i / BN) * BN;
    ushort4 u = {0, 0, 0, 0};
    if (f < CIN) u = *reinterpret_cast<const ushort4*>(&xb[(size_t)f * S + s0 + sl]);
    unsigned short vv[4] = {u.x, u.y, u.z, u.w};
#pragma unroll
    for (int j = 0; j < 4; j++) {
      int s_ = sl + j;
      zt[s_ * CP + (f ^ ((((s_) >> 2) & XM) << 3))] = vv[j];
    }
  }
  __syncthreads();

  int w = tid >> 6;
  int lane = tid & 63;
  int lm = lane & 15, kh = lane >> 4;
  int o0w = (w / WN) * (COUT / WM);
  int col0 = (w % WN) * (BN / WN);
  int obBase = o0w >> 4;

  f32x4 acc[MF][NF];
#pragma unroll
  for (int mf = 0; mf < MF; mf++)
#pragma unroll
    for (int nf = 0; nf < NF; nf++) acc[mf][nf] = (f32x4){0.f, 0.f, 0.f, 0.f};

#pragma unroll
  for (int cb = 0; cb < KPAD / 32; cb++) {
    s16x8 a[MF], b[NF];
#pragma unroll
    for (int mf = 0; mf < MF; mf++)
      a[mf] = *reinterpret_cast<const s16x8*>(&wl[((obBase + mf) * (KPAD / 32) + cb) * 512 + lane * 8]);
#pragma unroll
    for (int nf = 0; nf < NF; nf++) {
      int col = col0 + nf * 16 + lm;
      int off = (cb * 32 + kh * 8) ^ (((col >> 2) & XM) << 3);
      b[nf] = *reinterpret_cast<const s16x8*>(&zt[col * CP + off]);
    }
#pragma unroll
    for (int mf = 0; mf < MF; mf++)
#pragma unroll
      for (int nf = 0; nf < NF; nf++)
        acc[mf][nf] = __builtin_amdgcn_mfma_f32_16x16x32_bf16(a[mf], b[nf], acc[mf][nf], 0, 0, 0);
  }

  __syncthreads();
  unsigned short* ot = sh;
#pragma unroll
  for (int mf = 0; mf < MF; mf++)
#pragma unroll
    for (int nf = 0; nf < NF; nf++) {
      int col = col0 + nf * 16 + lm;
#pragma unroll
      for (int rr = 0; rr < 4; rr++) {
        int o = o0w + mf * 16 + kh * 4 + rr;
        ot[o * BNP + col] = f2bf(acc[mf][nf][rr]);
      }
    }
  __syncthreads();
  int NBLK = gridDim.x;
  constexpr int W = (BN / 4 < 64) ? BN / 4 : 64;
  for (int i = tid * 4; i < COUT * BN; i += 1024) {
    int o = i / BN, col = i - (i / BN) * BN;
    ushort4 v = *reinterpret_cast<const ushort4*>(&ot[o * BNP + col]);
    *reinterpret_cast<ushort4*>(&y[((size_t)bl * COUT + o) * S + s0 + col]) = v;
    float f0 = bf2f(v.x), f1 = bf2f(v.y), f2 = bf2f(v.z), f3 = bf2f(v.w);
    float s = f0 + f1 + f2 + f3;
    float s2 = f0 * f0 + f1 * f1 + f2 * f2 + f3 * f3;
    for (int off = W / 2; off; off >>= 1) {
      s += __shfl_down(s, off);
      s2 += __shfl_down(s2, off);
    }
    if ((tid & (W - 1)) == 0) {
      size_t po = (((size_t)bl * COUT + o) * NBLK + blockIdx.x) * 2;
      part[po] = s;
      part[po + 1] = s2;
    }
  }
}

// ---------------- reduce partials -> (mean, rsigma) -------------------------
__global__ __launch_bounds__(256) void k_statsR(const float* __restrict__ part,
                                                float* __restrict__ stats,
                                                int NBLK, float invS) {
  int c = blockIdx.x, C = gridDim.x, bl = blockIdx.y;
  const float* p = part + (((size_t)bl * C + c) * NBLK) * 2;
  float s = 0.f, s2 = 0.f;
  for (int i = threadIdx.x; i < NBLK; i += 256) {
    s += p[2 * i];
    s2 += p[2 * i + 1];
  }
  for (int off = 32; off; off >>= 1) {
    s += __shfl_down(s, off);
    s2 += __shfl_down(s2, off);
  }
  __shared__ float ls[4], ls2[4];
  int w = threadIdx.x >> 6;
  if ((threadIdx.x & 63) == 0) {
    ls[w] = s;
    ls2[w] = s2;
  }
  __syncthreads();
  if (threadIdx.x == 0) {
    float S1 = ls[0] + ls[1] + ls[2] + ls[3];
    float S2 = ls2[0] + ls2[1] + ls2[2] + ls2[3];
    float m = S1 * invS;
    float v = S2 * invS - m * m;
    stats[((size_t)bl * C + c) * 2 + 0] = m;
    stats[((size_t)bl * C + c) * 2 + 1] = rsqrtf(fmaxf(v, 0.f) + 1e-5f);
  }
}

// ---------------- temporal conv: named ping-pong depth-2 prefetch, BN=128 ---
template <int C, int TIN, int STRIDE, int BN>
__global__ __launch_bounds__(512) void k_convmma(const unsigned short* __restrict__ y,
                                                 const unsigned short* __restrict__ wf,
                                                 const float* __restrict__ statsY,
                                                 unsigned short* __restrict__ cbuf,
                                                 float* __restrict__ partC) {
  constexpr int TOUT = TIN / STRIDE;
  constexpr int SPAN = STRIDE * BN + 8;
  constexpr int CP = C + 8;
  constexpr int WM = (C >= 64) ? 2 : 1;
  constexpr int WN = 8 / WM;
  constexpr int MF = C / (16 * WM);
  constexpr int NF = BN / (16 * WN);
  constexpr int BNP = BN + 8;
  constexpr int XM = (C == 32) ? 3 : 7;
  constexpr int NCB = C / 32;
  constexpr int IT = KK * NCB;

  __shared__ unsigned short zt[SPAN * CP];
  static_assert(C * BNP <= SPAN * CP, "epilogue stage must fit in zt");

  int t0 = blockIdx.x * BN;
  int n = blockIdx.y;
  int bl = blockIdx.z;
  int tid = threadIdx.x;
  int tin0 = STRIDE * t0 - 4;

  int w = tid >> 6;
  int lane = tid & 63;
  int lm = lane & 15, kh = lane >> 4;
  int o0w = (w / WN) * (C / WM);
  int col0 = (w % WN) * (BN / WN);
  int obBase = o0w >> 4;

  const unsigned short* wbase = wf + lane * 8;
  // named ping-pong buffers, loads issued 2 iterations ahead
  s16x8 aA[MF], aB[MF];
#pragma unroll
  for (int mf = 0; mf < MF; mf++)
    aA[mf] = *reinterpret_cast<const s16x8*>(
        wbase + (((size_t)(obBase + mf) * NCB + 0) << 9));
  if (IT > 1) {
    constexpr int K1 = 1 / NCB, CB1 = 1 % NCB;
#pragma unroll
    for (int mf = 0; mf < MF; mf++)
      aB[mf] = *reinterpret_cast<const s16x8*>(
          wbase + ((((size_t)K1 * (C / 16) + obBase + mf) * NCB + CB1) << 9));
  }

  // stage normalized+relu input, transposed + write-swizzled
  const unsigned short* yb = y + ((size_t)bl * C) * NN * TIN + (size_t)n * TIN;
  const float* stY = statsY + (size_t)bl * 2 * C;
  for (int i = tid * 4; i < C * SPAN; i += 2048) {
    int ci = i / SPAN, r = i - ci * SPAN;
    int t = tin0 + r;
    const unsigned short* yrow = yb + (size_t)ci * NN * TIN;
    float m = stY[2 * ci], rs = stY[2 * ci + 1];
    float zv[4];
    if (t >= 0 && t + 4 <= TIN) {
      ushort4 u = *reinterpret_cast<const ushort4*>(&yrow[t]);
      zv[0] = fmaxf((bf2f(u.x) - m) * rs, 0.f);
      zv[1] = fmaxf((bf2f(u.y) - m) * rs, 0.f);
      zv[2] = fmaxf((bf2f(u.z) - m) * rs, 0.f);
      zv[3] = fmaxf((bf2f(u.w) - m) * rs, 0.f);
    } else {
#pragma unroll
      for (int j = 0; j < 4; j++) {
        int tj = t + j;
        zv[j] = (tj >= 0 && tj < TIN) ? fmaxf((bf2f(yrow[tj]) - m) * rs, 0.f) : 0.f;
      }
    }
    int xo = ((r >> 2) & XM) << 3;
#pragma unroll
    for (int j = 0; j < 4; j++) zt[(r + j) * CP + (ci ^ xo)] = f2bf(zv[j]);
  }

  f32x4 acc[MF][NF];
#pragma unroll
  for (int mf = 0; mf < MF; mf++)
#pragma unroll
    for (int nf = 0; nf < NF; nf++) acc[mf][nf] = (f32x4){0.f, 0.f, 0.f, 0.f};

  int rbase[NF];
#pragma unroll
  for (int nf = 0; nf < NF; nf++) rbase[nf] = STRIDE * (col0 + nf * 16 + lm);

  __syncthreads();  // zt ready

#pragma unroll
  for (int itp = 0; itp < IT; itp += 2) {
    // ---- even iteration (consumes aA, refills aA for itp+2) ----
    {
      const int k = itp / NCB, cb = itp % NCB;
      s16x8 b[NF];
#pragma unroll
      for (int nf = 0; nf < NF; nf++) {
        int r = rbase[nf] + k;
        int off = (cb * 32 + kh * 8) ^ (((r >> 2) & XM) << 3);
        b[nf] = *reinterpret_cast<const s16x8*>(&zt[r * CP + off]);
      }
#pragma unroll
      for (int mf = 0; mf < MF; mf++)
#pragma unroll
        for (int nf = 0; nf < NF; nf++)
          acc[mf][nf] = __builtin_amdgcn_mfma_f32_16x16x32_bf16(aA[mf], b[nf], acc[mf][nf], 0, 0, 0);
      if (itp + 2 < IT) {
        const int it2 = itp + 2;
        const int k2 = it2 / NCB, cb2 = it2 % NCB;
#pragma unroll
        for (int mf = 0; mf < MF; mf++)
          aA[mf] = *reinterpret_cast<const s16x8*>(
              wbase + ((((size_t)k2 * (C / 16) + obBase + mf) * NCB + cb2) << 9));
      }
    }
    // ---- odd iteration (consumes aB, refills aB for itp+3) ----
    if (itp + 1 < IT) {
      const int it1 = itp + 1;
      const int k = it1 / NCB, cb = it1 % NCB;
      s16x8 b[NF];
#pragma unroll
      for (int nf = 0; nf < NF; nf++) {
        int r = rbase[nf] + k;
        int off = (cb * 32 + kh * 8) ^ (((r >> 2) & XM) << 3);
        b[nf] = *reinterpret_cast<const s16x8*>(&zt[r * CP + off]);
      }
#pragma unroll
      for (int mf = 0; mf < MF; mf++)
#pragma unroll
        for (int nf = 0; nf < NF; nf++)
          acc[mf][nf] = __builtin_amdgcn_mfma_f32_16x16x32_bf16(aB[mf], b[nf], acc[mf][nf], 0, 0, 0);
      if (itp + 3 < IT) {
        const int it3 = itp + 3;
        const int k3 = it3 / NCB, cb3 = it3 % NCB;
#pragma unroll
        for (int mf = 0; mf < MF; mf++)
          aB[mf] = *reinterpret_cast<const s16x8*>(
              wbase + ((((size_t)k3 * (C / 16) + obBase + mf) * NCB + cb3) << 9));
      }
    }
  }

  // epilogue: stage D in LDS (reuse zt), coalesced writes + stats partials
  __syncthreads();
  unsigned short* ot = zt;
#pragma unroll
  for (int mf = 0; mf < MF; mf++)
#pragma unroll
    for (int nf = 0; nf < NF; nf++) {
      int col = col0 + nf * 16 + lm;
#pragma unroll
      for (int rr = 0; rr < 4; rr++) {
        int o = o0w + mf * 16 + kh * 4 + rr;
        ot[o * BNP + col] = f2bf(acc[mf][nf][rr]);
      }
    }
  __syncthreads();
  int pb = blockIdx.y * gridDim.x + blockIdx.x;
  constexpr int W = (BN / 4 < 64) ? BN / 4 : 64;
  for (int i = tid * 4; i < C * BN; i += 2048) {
    int o = i / BN, col = i - (i / BN) * BN;
    ushort4 v = *reinterpret_cast<const ushort4*>(&ot[o * BNP + col]);
    *reinterpret_cast<ushort4*>(&cbuf[(((size_t)bl * C + o) * NN + n) * TOUT + t0 + col]) = v;
    float f0 = bf2f(v.x), f1 = bf2f(v.y), f2 = bf2f(v.z), f3 = bf2f(v.w);
    float s = f0 + f1 + f2 + f3;
    float s2 = f0 * f0 + f1 * f1 + f2 * f2 + f3 * f3;
    for (int off = W / 2; off; off >>= 1) {
      s += __shfl_down(s, off);
      s2 += __shfl_down(s2, off);
    }
    if ((tid & (W - 1)) == 0) {
      size_t po = (((size_t)bl * C + o) * 248 + pb) * 2;
      partC[po] = s;
      partC[po + 1] = s2;
    }
  }
}

// ---------------- residual 1x1 + norm2 + relu epilogue as MFMA GEMM ---------
template <int CIN, int COUT, int TOUT, int STRIDE>
__global__ __launch_bounds__(256) void k_postmma(const unsigned short* __restrict__ cbuf,
                                                 const float* __restrict__ statsC,
                                                 const unsigned short* __restrict__ in,
                                                 const unsigned short* __restrict__ wrf,
                                                 const float* __restrict__ br,
                                                 unsigned short* __restrict__ out) {
  constexpr int BN = 128;
  constexpr int TIN_ = TOUT * STRIDE;
  constexpr int KPAD = (CIN <= 32) ? 32 : 64;
  constexpr int CP = KPAD + 8;
  constexpr int BNP = BN + 8;
  constexpr int MF = (COUT >= 64) ? COUT / 32 : 1;
  constexpr int NF = 4;
  constexpr int XM = (KPAD == 32) ? 3 : 7;
  constexpr int ZTSZ = BN * CP;
  constexpr int WLSZ = COUT * KPAD;
  constexpr int OTSZ = COUT * BNP;
  constexpr int SH = (ZTSZ + WLSZ > OTSZ) ? ZTSZ + WLSZ : OTSZ;
  __shared__ unsigned short sh[SH];
  __shared__ float stL[2 * COUT];
  __shared__ float brL[COUT];
  unsigned short* zt = sh;
  unsigned short* wl = sh + ZTSZ;

  int t0 = blockIdx.x * BN;
  int n = blockIdx.y;
  int bl = blockIdx.z;
  int tid = threadIdx.x;

  for (int i = tid; i < 2 * COUT; i += 256) stL[i] = statsC[(size_t)bl * 2 * COUT + i];
  if (tid < COUT) brL[tid] = br[tid];

  for (int i = tid * 4; i < WLSZ; i += 1024)
    *reinterpret_cast<ushort4*>(&wl[i]) = *reinterpret_cast<const ushort4*>(&wrf[i]);

  const unsigned short* ib = in + ((size_t)bl * CIN) * NN * TIN_ + (size_t)n * TIN_;
  for (int i = tid * 4; i < KPAD * BN; i += 1024) {
    int f = i / BN, sl = i - (i / BN) * BN;
    unsigned short vv[4] = {0, 0, 0, 0};
    if (f < CIN) {
      const unsigned short* row = ib + (size_t)f * NN * TIN_;
      if (STRIDE == 1) {
        ushort4 u = *reinterpret_cast<const ushort4*>(&row[t0 + sl]);
        vv[0] = u.x; vv[1] = u.y; vv[2] = u.z; vv[3] = u.w;
      } else {
        ushort4 u0 = *reinterpret_cast<const ushort4*>(&row[2 * (t0 + sl)]);
        ushort4 u1 = *reinterpret_cast<const ushort4*>(&row[2 * (t0 + sl) + 4]);
        vv[0] = u0.x; vv[1] = u0.z; vv[2] = u1.x; vv[3] = u1.z;
      }
    }
#pragma unroll
    for (int j = 0; j < 4; j++) {
      int s_ = sl + j;
      zt[s_ * CP + (f ^ ((((s_) >> 2) & XM) << 3))] = vv[j];
    }
  }
  __syncthreads();

  int w = tid >> 6;
  int lane = tid & 63;
  int lm = lane & 15, kh = lane >> 4;
  int o0w = (w / 2) * (COUT / 2);
  int col0 = (w % 2) * 64;
  int obBase = o0w >> 4;

  f32x4 acc[MF][NF];
#pragma unroll
  for (int mf = 0; mf < MF; mf++)
#pragma unroll
    for (int nf = 0; nf < NF; nf++) acc[mf][nf] = (f32x4){0.f, 0.f, 0.f, 0.f};

#pragma unroll
  for (int cb = 0; cb < KPAD / 32; cb++) {
    s16x8 a[MF], b[NF];
#pragma unroll
    for (int mf = 0; mf < MF; mf++)
      a[mf] = *reinterpret_cast<const s16x8*>(&wl[((obBase + mf) * (KPAD / 32) + cb) * 512 + lane * 8]);
#pragma unroll
    for (int nf = 0; nf < NF; nf++) {
      int col = col0 + nf * 16 + lm;
      int off = (cb * 32 + kh * 8) ^ (((col >> 2) & XM) << 3);
      b[nf] = *reinterpret_cast<const s16x8*>(&zt[col * CP + off]);
    }
#pragma unroll
    for (int mf = 0; mf < MF; mf++)
#pragma unroll
      for (int nf = 0; nf < NF; nf++)
        acc[mf][nf] = __builtin_amdgcn_mfma_f32_16x16x32_bf16(a[mf], b[nf], acc[mf][nf], 0, 0, 0);
  }

  __syncthreads();
  unsigned short* ot = sh;
#pragma unroll
  for (int mf = 0; mf < MF; mf++)
#pragma unroll
    for (int nf = 0; nf < NF; nf++) {
      int col = col0 + nf * 16 + lm;
#pragma unroll
      for (int rr = 0; rr < 4; rr++) {
        int o = o0w + mf * 16 + kh * 4 + rr;
        ot[o * BNP + col] = f2bf(acc[mf][nf][rr]);
      }
    }
  __syncthreads();
  for (int i = tid * 4; i < COUT * BN; i += 1024) {
    int o = i / BN, col = i - (i / BN) * BN;
    ushort4 rv = *reinterpret_cast<const ushort4*>(&ot[o * BNP + col]);
    ushort4 cv = *reinterpret_cast<const ushort4*>(&cbuf[(((size_t)bl * COUT + o) * NN + n) * TOUT + t0 + col]);
    float m = stL[2 * o], rs = stL[2 * o + 1], bb = brL[o];
    ushort4 ov;
    float v0 = fmaxf((bf2f(cv.x) - m) * rs, 0.f) + bf2f(rv.x) + bb;
    float v1 = fmaxf((bf2f(cv.y) - m) * rs, 0.f) + bf2f(rv.y) + bb;
    float v2 = fmaxf((bf2f(cv.z) - m) * rs, 0.f) + bf2f(rv.z) + bb;
    float v3 = fmaxf((bf2f(cv.w) - m) * rs, 0.f) + bf2f(rv.w) + bb;
    ov.x = f2bf(fmaxf(v0, 0.f));
    ov.y = f2bf(fmaxf(v1, 0.f));
    ov.z = f2bf(fmaxf(v2, 0.f));
    ov.w = f2bf(fmaxf(v3, 0.f));
    *reinterpret_cast<ushort4*>(&out[(((size_t)bl * COUT + o) * NN + n) * TOUT + t0 + col]) = ov;
  }
}

// ---------------- node-mean pool --------------------------------------------
__global__ __launch_bounds__(256) void k_pool(const unsigned short* __restrict__ src,
                                              float* __restrict__ pooled, int b0) {
  constexpr int CP2 = 128, TPZ = 512;
  int t = blockIdx.x * 64 + (threadIdx.x & 63);
  int c = blockIdx.y * 4 + (threadIdx.x >> 6);
  int bl = blockIdx.z;
  const unsigned short* p = src + ((size_t)bl * CP2 + c) * NN * TPZ + t;
  float s = 0.f;
  for (int n = 0; n < NN; n++) s += bf2f(p[(size_t)n * TPZ]);
  pooled[((size_t)(b0 + bl) * TPZ + t) * CP2 + c] = s * (1.f / NN);
}

// ---------------- attention scores ------------------------------------------
__global__ __launch_bounds__(128) void k_attn1(const float* __restrict__ pooled,
                                               const float* __restrict__ w1,
                                               const float* __restrict__ b1,
                                               const float* __restrict__ w2,
                                               const float* __restrict__ b2v,
                                               float* __restrict__ score) {
  __shared__ float w1L[128 * 64];
  __shared__ float w2L[64];
  __shared__ float b1L[64];
  int b = blockIdx.y;
  int t = blockIdx.x * 128 + threadIdx.x;
  int tid = threadIdx.x;
  for (int i = tid; i < 128 * 64; i += 128) w1L[i] = w1[i];
  if (tid < 64) {
    w2L[tid] = w2[tid];
    b1L[tid] = b1[tid];
  }
  __syncthreads();
  float hid[64];
#pragma unroll
  for (int j = 0; j < 64; j++) hid[j] = b1L[j];
  const float* pv = &pooled[((size_t)b * 512 + t) * 128];
  for (int c = 0; c < 128; c++) {
    float xv = pv[c];
#pragma unroll
    for (int j = 0; j < 64; j++) hid[j] += xv * w1L[c * 64 + j];
  }
  float s = b2v[0];
#pragma unroll
  for (int j = 0; j < 64; j++) s += tanhf(hid[j]) * w2L[j];
  score[(size_t)b * 512 + t] = s;
}

// ---------------- softmax over T'=512 per sample ----------------------------
__global__ __launch_bounds__(256) void k_attn2(const float* __restrict__ score,
                                               float* __restrict__ wgt) {
  __shared__ float sc[512];
  __shared__ float red[4];
  int b = blockIdx.x;
  int tid = threadIdx.x;
  for (int t = tid; t < 512; t += 256) sc[t] = score[(size_t)b * 512 + t];
  __syncthreads();
  float mx = -1e30f;
  for (int t = tid; t < 512; t += 256) mx = fmaxf(mx, sc[t]);
  for (int off = 32; off; off >>= 1) mx = fmaxf(mx, __shfl_down(mx, off));
  if ((tid & 63) == 0) red[tid >> 6] = mx;
  __syncthreads();
  mx = fmaxf(fmaxf(red[0], red[1]), fmaxf(red[2], red[3]));
  __syncthreads();
  float sum = 0.f;
  for (int t = tid; t < 512; t += 256) {
    float e = expf(sc[t] - mx);
    sc[t] = e;
    sum += e;
  }
  for (int off = 32; off; off >>= 1) sum += __shfl_down(sum, off);
  if ((tid & 63) == 0) red[tid >> 6] = sum;
  __syncthreads();
  float inv = 1.f / (red[0] + red[1] + red[2] + red[3]);
  for (int t = tid; t < 512; t += 256) wgt[(size_t)b * 512 + t] = sc[t] * inv;
}

// ---------------- weighted feature chunks -----------------------------------
__global__ __launch_bounds__(256) void k_feat2(const float* __restrict__ pooled,
                                               const float* __restrict__ wgt,
                                               float* __restrict__ featb) {
  __shared__ float sh[16][17];
  int b = blockIdx.y;
  int c0 = blockIdx.x * 16;
  int cl = threadIdx.x & 15, tlane = threadIdx.x >> 4;
  float s = 0.f;
  for (int t = tlane; t < 512; t += 16)
    s += pooled[((size_t)b * 512 + t) * 128 + c0 + cl] * wgt[(size_t)b * 512 + t];
  sh[tlane][cl] = s;
  __syncthreads();
  if (threadIdx.x < 16) {
    float a = 0.f;
    for (int q = 0; q < 16; q++) a += sh[q][threadIdx.x];
    featb[(size_t)b * 128 + c0 + threadIdx.x] = a;
  }
}

// ---------------- logits ----------------------------------------------------
__global__ __launch_bounds__(128) void k_logits(const float* __restrict__ featb,
                                                const float* __restrict__ fcw,
                                                const float* __restrict__ fcb,
                                                float* __restrict__ out) {
  __shared__ float fL[128];
  int b = blockIdx.x;
  fL[threadIdx.x] = featb[(size_t)b * 128 + threadIdx.x];
  __syncthreads();
  if (threadIdx.x < 3) {
    float l = fcb[threadIdx.x];
    for (int cc = 0; cc < 128; cc++) l += fL[cc] * fcw[cc * 3 + threadIdx.x];
    out[(size_t)b * 3 + threadIdx.x] = l;
  }
}

// ============================================================================
extern "C" void kernel_launch(void* const* d_in, const int* in_sizes, int n_in,
                              void* d_out, int out_size, void* d_ws, size_t ws_size,
                              hipStream_t stream) {
  (void)in_sizes; (void)n_in; (void)out_size;
  const float* x = (const float*)d_in[0];
  const float* adj = (const float*)d_in[1];
  const float* gw0 = (const float*)d_in[2];
  const float* cw0 = (const float*)d_in[4];
  const float* rw0 = (const float*)d_in[6];
  const float* rb0 = (const float*)d_in[7];
  const float* gw1 = (const float*)d_in[8];
  const float* cw1 = (const float*)d_in[10];
  const float* rw1 = (const float*)d_in[12];
  const float* rb1 = (const float*)d_in[13];
  const float* gw2 = (const float*)d_in[14];
  const float* cw2 = (const float*)d_in[16];
  const float* rw2 = (const float*)d_in[18];
  const float* rb2 = (const float*)d_in[19];
  const float* aw1 = (const float*)d_in[20];
  const float* ab1 = (const float*)d_in[21];
  const float* aw2 = (const float*)d_in[22];
  const float* ab2 = (const float*)d_in[23];
  const float* fcw = (const float*)d_in[24];
  const float* fcb = (const float*)d_in[25];
  float* out = (float*)d_out;
  float* ws = (float*)d_ws;

  // ---- shared ws region (sizes in floats) ----
  float* a_norm = ws;                                                      // 3844
  unsigned short* wk0 = (unsigned short*)(a_norm + 3844);                  // 4608 f
  unsigned short* wk1 = (unsigned short*)(a_norm + 8452);                  // 18432 f
  unsigned short* wk2 = (unsigned short*)(a_norm + 26884);                 // 73728 f
  unsigned short* wg0f = (unsigned short*)(a_norm + 100612);               // 512 f
  unsigned short* wg1f = (unsigned short*)(a_norm + 101124);               // 1024 f
  unsigned short* wg2f = (unsigned short*)(a_norm + 102148);               // 4096 f
  unsigned short* anf = (unsigned short*)(a_norm + 106244);                // 2048 f
  unsigned short* wr0f = (unsigned short*)(a_norm + 108292);               // 512 f
  unsigned short* wr1f = (unsigned short*)(a_norm + 108804);               // 1024 f
  unsigned short* wr2f = (unsigned short*)(a_norm + 109828);               // 4096 f
  float* pooled = a_norm + 113924;                                         // 2097152
  float* scoreb = pooled + 2097152;                                        // 16384
  float* wgtA = scoreb + 16384;                                            // 16384
  float* featb = wgtA + 16384;                                             // 4096
  float* chunk_base = featb + 4096;
  size_t shared_floats = (size_t)(chunk_base - ws);

  const size_t PS_BUF = 2031616;   // bf16 activation buffer (float slots)
  const size_t PS_P1 = 131072;     // wmix stats partials
  const size_t PS_P2 = 65536;      // conv stats partials
  const size_t per_sample = 3 * PS_BUF + PS_P1 + PS_P2 + 512;

  size_t avail = ws_size / sizeof(float);
  long cap = 1;
  if (avail > shared_floats) cap = (long)((avail - shared_floats) / per_sample);
  int Bc = (int)cap;
  if (Bc < 1) Bc = 1;
  if (Bc > 32) Bc = 32;

  // one-time prep: 2 launches total
  k_prep<<<dim3(1), dim3(256), 0, stream>>>(adj, a_norm, out + 96);
  k_wall<<<dim3(576, 10), dim3(256), 0, stream>>>(
      a_norm, anf, cw0, wk0, cw1, wk1, cw2, wk2,
      gw0, wg0f, gw1, wg1f, gw2, wg2f, rw0, wr0f, rw1, wr1f, rw2, wr2f);

  float* sp1 = chunk_base;                        // Bc*131072
  float* sp2 = sp1 + (size_t)Bc * PS_P1;          // Bc*65536
  float* stY = sp2 + (size_t)Bc * PS_P2;          // Bc*256
  float* stC = stY + (size_t)Bc * 256;            // Bc*256
  float* B1 = stC + (size_t)Bc * 256;
  float* B2 = B1 + (size_t)Bc * PS_BUF;
  float* B3 = B2 + (size_t)Bc * PS_BUF;

  for (int b0 = 0; b0 < 32; b0 += Bc) {
    int bc = (32 - b0 < Bc) ? (32 - b0) : Bc;
    unsigned short* B1u = (unsigned short*)B1;
    unsigned short* B2u = (unsigned short*)B2;
    unsigned short* B3u = (unsigned short*)B3;

    // ---- block 0: 5 -> 32, T 1024, stride 1 ----
    k_xcast<<<dim3(4, NN, bc), dim3(256), 0, stream>>>(x, B1u, b0);
    k_spatmma<5, 1024><<<dim3(4, 5, bc), dim3(256), 0, stream>>>(B1u, anf, B2u);
    k_wmixmma<5, 32, 1024><<<dim3(248, bc), dim3(256), 0, stream>>>(B2u, wg0f, B3u, sp1);
    k_statsR<<<dim3(32, bc), dim3(256), 0, stream>>>(sp1, stY, 248, 1.f / 63488.f);
    k_convmma<32, 1024, 1, 256><<<dim3(4, NN, bc), dim3(512), 0, stream>>>(B3u, wk0, stY, B2u, sp2);
    k_statsR<<<dim3(32, bc), dim3(256), 0, stream>>>(sp2, stC, 248, 1.f / 63488.f);
    k_postmma<5, 32, 1024, 1><<<dim3(8, NN, bc), dim3(256), 0, stream>>>(
        B2u, stC, B1u, wr0f, rb0, B3u);  // A -> B3u

    // ---- block 1: 32 -> 64, T 1024->512, stride 2; in = A (B3u) ----
    k_spatmma<32, 1024><<<dim3(4, 32, bc), dim3(256), 0, stream>>>(B3u, anf, B1u);
    k_wmixmma<32, 64, 1024><<<dim3(248, bc), dim3(256), 0, stream>>>(B1u, wg1f, B2u, sp1);
    k_statsR<<<dim3(64, bc), dim3(256), 0, stream>>>(sp1, stY, 248, 1.f / 63488.f);
    k_convmma<64, 1024, 2, 128><<<dim3(4, NN, bc), dim3(512), 0, stream>>>(B2u, wk1, stY, B1u, sp2);
    k_statsR<<<dim3(64, bc), dim3(256), 0, stream>>>(sp2, stC, 248, 1.f / 31744.f);
    k_postmma<32, 64, 512, 2><<<dim3(4, NN, bc), dim3(256), 0, stream>>>(
        B1u, stC, B3u, wr1f, rb1, B2u);  // D -> B2u

    // ---- block 2: 64 -> 128, T 512, stride 1; in = D (B2u) ----
    k_spatmma<64, 512><<<dim3(2, 64, bc), dim3(256), 0, stream>>>(B2u, anf, B3u);
    k_wmixmma<64, 128, 512><<<dim3(248, bc), dim3(256), 0, stream>>>(B3u, wg2f, B1u, sp1);
    k_statsR<<<dim3(128, bc), dim3(256), 0, stream>>>(sp1, stY, 248, 1.f / 31744.f);
    k_convmma<128, 512, 1, 128><<<dim3(4, NN, bc), dim3(512), 0, stream>>>(B1u, wk2, stY, B3u, sp2);
    k_statsR<<<dim3(128, bc), dim3(256), 0, stream>>>(sp2, stC, 248, 1.f / 31744.f);
    k_postmma<64, 128, 512, 1><<<dim3(4, NN, bc), dim3(256), 0, stream>>>(
        B3u, stC, B2u, wr2f, rb2, B1u);  // OUT -> B1u

    k_pool<<<dim3(8, 32, bc), dim3(256), 0, stream>>>(B1u, pooled, b0);
  }

  // ---- head: full batch at once (fp32) ----
  k_attn1<<<dim3(4, 32), dim3(128), 0, stream>>>(pooled, aw1, ab1, aw2, ab2, scoreb);
  k_attn2<<<dim3(32), dim3(256), 0, stream>>>(scoreb, wgtA);
  k_feat2<<<dim3(8, 32), dim3(256), 0, stream>>>(pooled, wgtA, featb);
  k_logits<<<dim3(32), dim3(128), 0, stream>>>(featb, fcw, fcb, out);
}

// Round 18
// 1998.764 us; speedup vs baseline: 1.1569x; 1.1569x over previous
//
#include <hip/hip_runtime.h>

// ST-GCN classifier forward. Round 18: FINAL — round-16 restored verbatim
// (empirical best, 2.000 ms, absmax 2.9e-3). Conv k-loop = r10 depth-1
// prefetch (44 VGPR / 42% occ — proven optimal across 7 variants);
// k_statsR pipeline; merged one-launch weight prep.

#define NN 62
#define KK 9

typedef short s16x8 __attribute__((ext_vector_type(8)));
typedef float f32x4 __attribute__((ext_vector_type(4)));

__device__ __forceinline__ unsigned short f2bf(float f) {
  unsigned u = __builtin_bit_cast(unsigned, f);
  u += 0x7FFF + ((u >> 16) & 1);
  return (unsigned short)(u >> 16);
}
__device__ __forceinline__ float bf2f(unsigned short u) {
  unsigned v = ((unsigned)u) << 16;
  return __builtin_bit_cast(float, v);
}
__device__ __forceinline__ ushort4 pack4(float4 a) {
  return (ushort4){f2bf(a.x), f2bf(a.y), f2bf(a.z), f2bf(a.w)};
}

// ---------------- prep: gcn-normalized adjacency + adj passthrough ----------
__global__ __launch_bounds__(256) void k_prep(const float* __restrict__ adj,
                                              float* __restrict__ a_norm,
                                              float* __restrict__ out_adj) {
  __shared__ float dinv[NN];
  int tid = threadIdx.x;
  if (tid < NN) {
    float s = 1.0f;
    for (int n = 0; n < NN; n++) s += adj[tid * NN + n];
    dinv[tid] = (s > 0.f) ? rsqrtf(fmaxf(s, 1e-5f)) : 0.f;
  }
  __syncthreads();
  for (int idx = tid; idx < NN * NN; idx += 256) {
    int m = idx / NN, n = idx - m * NN;
    float ah = adj[idx] + ((m == n) ? 1.f : 0.f);
    a_norm[idx] = dinv[m] * ah * dinv[n];
    out_adj[idx] = adj[idx];
  }
}

// ------------- device helpers for weight layout transforms ------------------
__device__ __forceinline__ void wt_fill(const float* __restrict__ wc,
                                        unsigned short* __restrict__ wf, int C, int idx) {
  int total = KK * C * C;
  if (idx >= total) return;
  int nCB = C / 32;
  int j = idx & 7;
  int l = (idx >> 3) & 63;
  int rest = idx >> 9;
  int cb = rest % nCB;
  int rest2 = rest / nCB;
  int ob = rest2 % (C / 16);
  int k = rest2 / (C / 16);
  int o = ob * 16 + (l & 15);
  int ci = cb * 32 + (l >> 4) * 8 + j;
  wf[idx] = f2bf(wc[((size_t)o * C + ci) * KK + k]);
}
__device__ __forceinline__ void wg_fill(const float* __restrict__ gw,
                                        unsigned short* __restrict__ wgf,
                                        int CIN, int COUT, int KPAD, int idx) {
  int total = (COUT / 16) * (KPAD / 32) * 512;
  if (idx >= total) return;
  int j = idx & 7;
  int l = (idx >> 3) & 63;
  int rest = idx >> 9;
  int cb = rest % (KPAD / 32);
  int ob = rest / (KPAD / 32);
  int o = ob * 16 + (l & 15);
  int f = cb * 32 + (l >> 4) * 8 + j;
  wgf[idx] = (f < CIN) ? f2bf(gw[(size_t)f * COUT + o]) : (unsigned short)0;
}
__device__ __forceinline__ void wr_fill(const float* __restrict__ wr,
                                        unsigned short* __restrict__ wrf,
                                        int CIN, int COUT, int KPAD, int idx) {
  int total = (COUT / 16) * (KPAD / 32) * 512;
  if (idx >= total) return;
  int j = idx & 7;
  int l = (idx >> 3) & 63;
  int rest = idx >> 9;
  int cb = rest % (KPAD / 32);
  int ob = rest / (KPAD / 32);
  int o = ob * 16 + (l & 15);
  int f = cb * 32 + (l >> 4) * 8 + j;
  wrf[idx] = (f < CIN) ? f2bf(wr[(size_t)o * CIN + f]) : (unsigned short)0;
}

// ------------- unified one-launch weight prep (segment = blockIdx.y) --------
__global__ __launch_bounds__(256) void k_wall(
    const float* __restrict__ a_norm, unsigned short* __restrict__ anf,
    const float* __restrict__ cw0, unsigned short* __restrict__ wk0,
    const float* __restrict__ cw1, unsigned short* __restrict__ wk1,
    const float* __restrict__ cw2, unsigned short* __restrict__ wk2,
    const float* __restrict__ gw0, unsigned short* __restrict__ wg0f,
    const float* __restrict__ gw1, unsigned short* __restrict__ wg1f,
    const float* __restrict__ gw2, unsigned short* __restrict__ wg2f,
    const float* __restrict__ rw0, unsigned short* __restrict__ wr0f,
    const float* __restrict__ rw1, unsigned short* __restrict__ wr1f,
    const float* __restrict__ rw2, unsigned short* __restrict__ wr2f) {
  int idx = blockIdx.x * 256 + threadIdx.x;
  switch (blockIdx.y) {
    case 0: {
      if (idx < 4096) {
        int j = idx & 7;
        int l = (idx >> 3) & 63;
        int rest = idx >> 9;
        int cb = rest & 1;
        int ob = rest >> 1;
        int m = ob * 16 + (l & 15);
        int n = cb * 32 + (l >> 4) * 8 + j;
        anf[idx] = (m < NN && n < NN) ? f2bf(a_norm[m * NN + n]) : (unsigned short)0;
      }
      break;
    }
    case 1: wt_fill(cw0, wk0, 32, idx); break;
    case 2: wt_fill(cw1, wk1, 64, idx); break;
    case 3: wt_fill(cw2, wk2, 128, idx); break;
    case 4: wg_fill(gw0, wg0f, 5, 32, 32, idx); break;
    case 5: wg_fill(gw1, wg1f, 32, 64, 32, idx); break;
    case 6: wg_fill(gw2, wg2f, 64, 128, 64, idx); break;
    case 7: wr_fill(rw0, wr0f, 5, 32, 32, idx); break;
    case 8: wr_fill(rw1, wr1f, 32, 64, 32, idx); break;
    case 9: wr_fill(rw2, wr2f, 64, 128, 64, idx); break;
  }
}

// ---------------- x cast: (b0+bl, n, t, f=5) fp32 -> [bl][f][n][t] bf16 -----
__global__ __launch_bounds__(256) void k_xcast(const float* __restrict__ x,
                                               unsigned short* __restrict__ xb, int b0) {
  constexpr int TT2 = 256, TIN = 1024, CIN = 5;
  __shared__ float xt[TT2 * CIN];
  int t0 = blockIdx.x * TT2, n = blockIdx.y, bl = blockIdx.z;
  int tid = threadIdx.x;
  const float* xp = x + ((size_t)((b0 + bl) * NN + n) * TIN + t0) * CIN;
  for (int i = tid; i < TT2 * CIN; i += 256) xt[i] = xp[i];
  __syncthreads();
  for (int i = tid; i < CIN * TT2; i += 256) {
    int f = i / TT2, tl = i - f * TT2;
    xb[((size_t)bl * CIN + f) * NN * TIN + (size_t)n * TIN + t0 + tl] = f2bf(xt[tl * CIN + f]);
  }
}

// ---------------- spatial A-mix as bf16 MFMA GEMM ---------------------------
template <int CIN, int TIN>
__global__ __launch_bounds__(256) void k_spatmma(const unsigned short* __restrict__ in,
                                                 const unsigned short* __restrict__ anf,
                                                 unsigned short* __restrict__ xs) {
  constexpr int BT = 256;
  constexpr int CP = 72;
  constexpr int BNP = BT + 8;
  constexpr int ZTSZ = BT * CP;
  constexpr int WLSZ = 4096;
  constexpr int OTSZ = 64 * BNP;
  constexpr int SH = (ZTSZ + WLSZ > OTSZ) ? ZTSZ + WLSZ : OTSZ;
  __shared__ unsigned short sh[SH];
  unsigned short* zt = sh;
  unsigned short* wl = sh + ZTSZ;

  int t0 = blockIdx.x * BT;
  int f = blockIdx.y;
  int bl = blockIdx.z;
  int tid = threadIdx.x;

  for (int i = tid * 4; i < WLSZ; i += 1024)
    *reinterpret_cast<ushort4*>(&wl[i]) = *reinterpret_cast<const ushort4*>(&anf[i]);

  const unsigned short* ib = in + ((size_t)bl * CIN + f) * (size_t)NN * TIN;
  for (int i = tid * 4; i < 64 * BT; i += 1024) {
    int n = i / BT, tl = i - n * BT;
    ushort4 u = {0, 0, 0, 0};
    if (n < NN) u = *reinterpret_cast<const ushort4*>(&ib[(size_t)n * TIN + t0 + tl]);
    unsigned short vv[4] = {u.x, u.y, u.z, u.w};
    int xo = ((tl >> 2) & 7) << 3;
#pragma unroll
    for (int j = 0; j < 4; j++) zt[(tl + j) * CP + (n ^ xo)] = vv[j];
  }
  __syncthreads();

  int w = tid >> 6;
  int lane = tid & 63;
  int lm = lane & 15, kh = lane >> 4;
  int col0 = w * 64;

  f32x4 acc[4][4];
#pragma unroll
  for (int mf = 0; mf < 4; mf++)
#pragma unroll
    for (int nf = 0; nf < 4; nf++) acc[mf][nf] = (f32x4){0.f, 0.f, 0.f, 0.f};

#pragma unroll
  for (int cb = 0; cb < 2; cb++) {
    s16x8 a[4], b[4];
#pragma unroll
    for (int mf = 0; mf < 4; mf++)
      a[mf] = *reinterpret_cast<const s16x8*>(&wl[(mf * 2 + cb) * 512 + lane * 8]);
#pragma unroll
    for (int nf = 0; nf < 4; nf++) {
      int col = col0 + nf * 16 + lm;
      int off = (cb * 32 + kh * 8) ^ (((col >> 2) & 7) << 3);
      b[nf] = *reinterpret_cast<const s16x8*>(&zt[col * CP + off]);
    }
#pragma unroll
    for (int mf = 0; mf < 4; mf++)
#pragma unroll
      for (int nf = 0; nf < 4; nf++)
        acc[mf][nf] = __builtin_amdgcn_mfma_f32_16x16x32_bf16(a[mf], b[nf], acc[mf][nf], 0, 0, 0);
  }

  __syncthreads();
  unsigned short* ot = sh;
#pragma unroll
  for (int mf = 0; mf < 4; mf++)
#pragma unroll
    for (int nf = 0; nf < 4; nf++) {
      int col = col0 + nf * 16 + lm;
#pragma unroll
      for (int rr = 0; rr < 4; rr++) {
        int m = mf * 16 + kh * 4 + rr;
        ot[m * BNP + col] = f2bf(acc[mf][nf][rr]);
      }
    }
  __syncthreads();
  for (int i = tid * 4; i < NN * BT; i += 1024) {
    int m = i / BT, col = i - m * BT;
    ushort4 v = *reinterpret_cast<const ushort4*>(&ot[m * BNP + col]);
    *reinterpret_cast<ushort4*>(&xs[(((size_t)bl * CIN + f) * NN + m) * TIN + t0 + col]) = v;
  }
}

// ---------------- channel mix as bf16 MFMA GEMM + fused stats ---------------
template <int CIN, int COUT, int TIN>
__global__ __launch_bounds__(256) void k_wmixmma(const unsigned short* __restrict__ xs,
                                                 const unsigned short* __restrict__ wgf,
                                                 unsigned short* __restrict__ y,
                                                 float* __restrict__ part) {
  constexpr int S = NN * TIN;
  constexpr int KPAD = (CIN <= 32) ? 32 : 64;
  constexpr int CP = KPAD + 8;
  constexpr int BN = (COUT >= 128) ? 128 : 256;
  constexpr int BNP = BN + 8;
  constexpr int WM = (COUT >= 64) ? 2 : 1;
  constexpr int WN = 4 / WM;
  constexpr int MF = COUT / (16 * WM);
  constexpr int NF = BN / (16 * WN);
  constexpr int XM = (KPAD == 32) ? 3 : 7;
  constexpr int ZTSZ = BN * CP;
  constexpr int WLSZ = COUT * KPAD;
  constexpr int OTSZ = COUT * BNP;
  constexpr int SH = (ZTSZ + WLSZ > OTSZ) ? ZTSZ + WLSZ : OTSZ;
  __shared__ unsigned short sh[SH];
  unsigned short* zt = sh;
  unsigned short* wl = sh + ZTSZ;

  int s0 = blockIdx.x * BN;
  int bl = blockIdx.y;
  int tid = threadIdx.x;

  for (int i = tid * 4; i < WLSZ; i += 1024)
    *reinterpret_cast<ushort4*>(&wl[i]) = *reinterpret_cast<const ushort4*>(&wgf[i]);

  const unsigned short* xb = xs + (size_t)bl * CIN * S;
  for (int i = tid * 4; i < KPAD * BN; i += 1024) {
    int f = i / BN, sl = i - (i / BN) * BN;
    ushort4 u = {0, 0, 0, 0};
    if (f < CIN) u = *reinterpret_cast<const ushort4*>(&xb[(size_t)f * S + s0 + sl]);
    unsigned short vv[4] = {u.x, u.y, u.z, u.w};
#pragma unroll
    for (int j = 0; j < 4; j++) {
      int s_ = sl + j;
      zt[s_ * CP + (f ^ ((((s_) >> 2) & XM) << 3))] = vv[j];
    }
  }
  __syncthreads();

  int w = tid >> 6;
  int lane = tid & 63;
  int lm = lane & 15, kh = lane >> 4;
  int o0w = (w / WN) * (COUT / WM);
  int col0 = (w % WN) * (BN / WN);
  int obBase = o0w >> 4;

  f32x4 acc[MF][NF];
#pragma unroll
  for (int mf = 0; mf < MF; mf++)
#pragma unroll
    for (int nf = 0; nf < NF; nf++) acc[mf][nf] = (f32x4){0.f, 0.f, 0.f, 0.f};

#pragma unroll
  for (int cb = 0; cb < KPAD / 32; cb++) {
    s16x8 a[MF], b[NF];
#pragma unroll
    for (int mf = 0; mf < MF; mf++)
      a[mf] = *reinterpret_cast<const s16x8*>(&wl[((obBase + mf) * (KPAD / 32) + cb) * 512 + lane * 8]);
#pragma unroll
    for (int nf = 0; nf < NF; nf++) {
      int col = col0 + nf * 16 + lm;
      int off = (cb * 32 + kh * 8) ^ (((col >> 2) & XM) << 3);
      b[nf] = *reinterpret_cast<const s16x8*>(&zt[col * CP + off]);
    }
#pragma unroll
    for (int mf = 0; mf < MF; mf++)
#pragma unroll
      for (int nf = 0; nf < NF; nf++)
        acc[mf][nf] = __builtin_amdgcn_mfma_f32_16x16x32_bf16(a[mf], b[nf], acc[mf][nf], 0, 0, 0);
  }

  __syncthreads();
  unsigned short* ot = sh;
#pragma unroll
  for (int mf = 0; mf < MF; mf++)
#pragma unroll
    for (int nf = 0; nf < NF; nf++) {
      int col = col0 + nf * 16 + lm;
#pragma unroll
      for (int rr = 0; rr < 4; rr++) {
        int o = o0w + mf * 16 + kh * 4 + rr;
        ot[o * BNP + col] = f2bf(acc[mf][nf][rr]);
      }
    }
  __syncthreads();
  int NBLK = gridDim.x;
  constexpr int W = (BN / 4 < 64) ? BN / 4 : 64;
  for (int i = tid * 4; i < COUT * BN; i += 1024) {
    int o = i / BN, col = i - (i / BN) * BN;
    ushort4 v = *reinterpret_cast<const ushort4*>(&ot[o * BNP + col]);
    *reinterpret_cast<ushort4*>(&y[((size_t)bl * COUT + o) * S + s0 + col]) = v;
    float f0 = bf2f(v.x), f1 = bf2f(v.y), f2 = bf2f(v.z), f3 = bf2f(v.w);
    float s = f0 + f1 + f2 + f3;
    float s2 = f0 * f0 + f1 * f1 + f2 * f2 + f3 * f3;
    for (int off = W / 2; off; off >>= 1) {
      s += __shfl_down(s, off);
      s2 += __shfl_down(s2, off);
    }
    if ((tid & (W - 1)) == 0) {
      size_t po = (((size_t)bl * COUT + o) * NBLK + blockIdx.x) * 2;
      part[po] = s;
      part[po + 1] = s2;
    }
  }
}

// ---------------- reduce partials -> (mean, rsigma) -------------------------
__global__ __launch_bounds__(256) void k_statsR(const float* __restrict__ part,
                                                float* __restrict__ stats,
                                                int NBLK, float invS) {
  int c = blockIdx.x, C = gridDim.x, bl = blockIdx.y;
  const float* p = part + (((size_t)bl * C + c) * NBLK) * 2;
  float s = 0.f, s2 = 0.f;
  for (int i = threadIdx.x; i < NBLK; i += 256) {
    s += p[2 * i];
    s2 += p[2 * i + 1];
  }
  for (int off = 32; off; off >>= 1) {
    s += __shfl_down(s, off);
    s2 += __shfl_down(s2, off);
  }
  __shared__ float ls[4], ls2[4];
  int w = threadIdx.x >> 6;
  if ((threadIdx.x & 63) == 0) {
    ls[w] = s;
    ls2[w] = s2;
  }
  __syncthreads();
  if (threadIdx.x == 0) {
    float S1 = ls[0] + ls[1] + ls[2] + ls[3];
    float S2 = ls2[0] + ls2[1] + ls2[2] + ls2[3];
    float m = S1 * invS;
    float v = S2 * invS - m * m;
    stats[((size_t)bl * C + c) * 2 + 0] = m;
    stats[((size_t)bl * C + c) * 2 + 1] = rsqrtf(fmaxf(v, 0.f) + 1e-5f);
  }
}

// ---------------- temporal conv (r10/r14/r16 version, best measured) --------
template <int C, int TIN, int STRIDE, int BN>
__global__ __launch_bounds__(512) void k_convmma(const unsigned short* __restrict__ y,
                                                 const unsigned short* __restrict__ wf,
                                                 const float* __restrict__ statsY,
                                                 unsigned short* __restrict__ cbuf,
                                                 float* __restrict__ partC) {
  constexpr int TOUT = TIN / STRIDE;
  constexpr int SPAN = STRIDE * BN + 8;
  constexpr int CP = C + 8;
  constexpr int WM = (C >= 64) ? 2 : 1;
  constexpr int WN = 8 / WM;
  constexpr int MF = C / (16 * WM);
  constexpr int NF = BN / (16 * WN);
  constexpr int BNP = BN + 8;
  constexpr int XM = (C == 32) ? 3 : 7;
  constexpr int NCB = C / 32;
  constexpr int IT = KK * NCB;

  __shared__ unsigned short zt[SPAN * CP];
  static_assert(C * BNP <= SPAN * CP, "epilogue stage must fit in zt");

  int t0 = blockIdx.x * BN;
  int n = blockIdx.y;
  int bl = blockIdx.z;
  int tid = threadIdx.x;
  int tin0 = STRIDE * t0 - 4;

  int w = tid >> 6;
  int lane = tid & 63;
  int lm = lane & 15, kh = lane >> 4;
  int o0w = (w / WN) * (C / WM);
  int col0 = (w % WN) * (BN / WN);
  int obBase = o0w >> 4;

  // per-mf weight pointers; issue first fragment loads before staging
  const unsigned short* wp[MF];
  s16x8 acur[MF], anxt[MF];
#pragma unroll
  for (int mf = 0; mf < MF; mf++) {
    wp[mf] = wf + ((size_t)(obBase + mf) * NCB) * 512 + lane * 8;
    acur[mf] = *reinterpret_cast<const s16x8*>(wp[mf]);
  }

  // stage normalized+relu input, transposed + write-swizzled
  const unsigned short* yb = y + ((size_t)bl * C) * NN * TIN + (size_t)n * TIN;
  const float* stY = statsY + (size_t)bl * 2 * C;
  for (int i = tid * 4; i < C * SPAN; i += 2048) {
    int ci = i / SPAN, r = i - ci * SPAN;
    int t = tin0 + r;
    const unsigned short* yrow = yb + (size_t)ci * NN * TIN;
    float m = stY[2 * ci], rs = stY[2 * ci + 1];
    float zv[4];
    if (t >= 0 && t + 4 <= TIN) {
      ushort4 u = *reinterpret_cast<const ushort4*>(&yrow[t]);
      zv[0] = fmaxf((bf2f(u.x) - m) * rs, 0.f);
      zv[1] = fmaxf((bf2f(u.y) - m) * rs, 0.f);
      zv[2] = fmaxf((bf2f(u.z) - m) * rs, 0.f);
      zv[3] = fmaxf((bf2f(u.w) - m) * rs, 0.f);
    } else {
#pragma unroll
      for (int j = 0; j < 4; j++) {
        int tj = t + j;
        zv[j] = (tj >= 0 && tj < TIN) ? fmaxf((bf2f(yrow[tj]) - m) * rs, 0.f) : 0.f;
      }
    }
    int xo = ((r >> 2) & XM) << 3;
#pragma unroll
    for (int j = 0; j < 4; j++) zt[(r + j) * CP + (ci ^ xo)] = f2bf(zv[j]);
  }

  f32x4 acc[MF][NF];
#pragma unroll
  for (int mf = 0; mf < MF; mf++)
#pragma unroll
    for (int nf = 0; nf < NF; nf++) acc[mf][nf] = (f32x4){0.f, 0.f, 0.f, 0.f};

  __syncthreads();  // zt ready

  for (int it = 0; it < IT; ++it) {
    int k = it / NCB, cb = it - (it / NCB) * NCB;
    if (it + 1 < IT) {
      int it2 = it + 1;
      int k2 = it2 / NCB, cb2 = it2 - (it2 / NCB) * NCB;
#pragma unroll
      for (int mf = 0; mf < MF; mf++)
        anxt[mf] = *reinterpret_cast<const s16x8*>(
            &wf[((((size_t)k2 * (C / 16) + obBase + mf) * NCB + cb2) << 9) + lane * 8]);
    }
    s16x8 b[NF];
#pragma unroll
    for (int nf = 0; nf < NF; nf++) {
      int col = col0 + nf * 16 + lm;
      int r = STRIDE * col + k;
      int off = (cb * 32 + kh * 8) ^ (((r >> 2) & XM) << 3);
      b[nf] = *reinterpret_cast<const s16x8*>(&zt[r * CP + off]);
    }
#pragma unroll
    for (int mf = 0; mf < MF; mf++)
#pragma unroll
      for (int nf = 0; nf < NF; nf++)
        acc[mf][nf] = __builtin_amdgcn_mfma_f32_16x16x32_bf16(acur[mf], b[nf], acc[mf][nf], 0, 0, 0);
    if (it + 1 < IT) {
#pragma unroll
      for (int mf = 0; mf < MF; mf++) acur[mf] = anxt[mf];
    }
  }

  // epilogue: stage D in LDS (reuse zt), coalesced writes + stats partials
  __syncthreads();
  unsigned short* ot = zt;
#pragma unroll
  for (int mf = 0; mf < MF; mf++)
#pragma unroll
    for (int nf = 0; nf < NF; nf++) {
      int col = col0 + nf * 16 + lm;
#pragma unroll
      for (int rr = 0; rr < 4; rr++) {
        int o = o0w + mf * 16 + kh * 4 + rr;
        ot[o * BNP + col] = f2bf(acc[mf][nf][rr]);
      }
    }
  __syncthreads();
  int pb = blockIdx.y * gridDim.x + blockIdx.x;
  constexpr int W = (BN / 4 < 64) ? BN / 4 : 64;
  for (int i = tid * 4; i < C * BN; i += 2048) {
    int o = i / BN, col = i - (i / BN) * BN;
    ushort4 v = *reinterpret_cast<const ushort4*>(&ot[o * BNP + col]);
    *reinterpret_cast<ushort4*>(&cbuf[(((size_t)bl * C + o) * NN + n) * TOUT + t0 + col]) = v;
    float f0 = bf2f(v.x), f1 = bf2f(v.y), f2 = bf2f(v.z), f3 = bf2f(v.w);
    float s = f0 + f1 + f2 + f3;
    float s2 = f0 * f0 + f1 * f1 + f2 * f2 + f3 * f3;
    for (int off = W / 2; off; off >>= 1) {
      s += __shfl_down(s, off);
      s2 += __shfl_down(s2, off);
    }
    if ((tid & (W - 1)) == 0) {
      size_t po = (((size_t)bl * C + o) * 248 + pb) * 2;
      partC[po] = s;
      partC[po + 1] = s2;
    }
  }
}

// ---------------- residual 1x1 + norm2 + relu epilogue as MFMA GEMM ---------
template <int CIN, int COUT, int TOUT, int STRIDE>
__global__ __launch_bounds__(256) void k_postmma(const unsigned short* __restrict__ cbuf,
                                                 const float* __restrict__ statsC,
                                                 const unsigned short* __restrict__ in,
                                                 const unsigned short* __restrict__ wrf,
                                                 const float* __restrict__ br,
                                                 unsigned short* __restrict__ out) {
  constexpr int BN = 128;
  constexpr int TIN_ = TOUT * STRIDE;
  constexpr int KPAD = (CIN <= 32) ? 32 : 64;
  constexpr int CP = KPAD + 8;
  constexpr int BNP = BN + 8;
  constexpr int MF = (COUT >= 64) ? COUT / 32 : 1;
  constexpr int NF = 4;
  constexpr int XM = (KPAD == 32) ? 3 : 7;
  constexpr int ZTSZ = BN * CP;
  constexpr int WLSZ = COUT * KPAD;
  constexpr int OTSZ = COUT * BNP;
  constexpr int SH = (ZTSZ + WLSZ > OTSZ) ? ZTSZ + WLSZ : OTSZ;
  __shared__ unsigned short sh[SH];
  __shared__ float stL[2 * COUT];
  __shared__ float brL[COUT];
  unsigned short* zt = sh;
  unsigned short* wl = sh + ZTSZ;

  int t0 = blockIdx.x * BN;
  int n = blockIdx.y;
  int bl = blockIdx.z;
  int tid = threadIdx.x;

  for (int i = tid; i < 2 * COUT; i += 256) stL[i] = statsC[(size_t)bl * 2 * COUT + i];
  if (tid < COUT) brL[tid] = br[tid];

  for (int i = tid * 4; i < WLSZ; i += 1024)
    *reinterpret_cast<ushort4*>(&wl[i]) = *reinterpret_cast<const ushort4*>(&wrf[i]);

  const unsigned short* ib = in + ((size_t)bl * CIN) * NN * TIN_ + (size_t)n * TIN_;
  for (int i = tid * 4; i < KPAD * BN; i += 1024) {
    int f = i / BN, sl = i - (i / BN) * BN;
    unsigned short vv[4] = {0, 0, 0, 0};
    if (f < CIN) {
      const unsigned short* row = ib + (size_t)f * NN * TIN_;
      if (STRIDE == 1) {
        ushort4 u = *reinterpret_cast<const ushort4*>(&row[t0 + sl]);
        vv[0] = u.x; vv[1] = u.y; vv[2] = u.z; vv[3] = u.w;
      } else {
        ushort4 u0 = *reinterpret_cast<const ushort4*>(&row[2 * (t0 + sl)]);
        ushort4 u1 = *reinterpret_cast<const ushort4*>(&row[2 * (t0 + sl) + 4]);
        vv[0] = u0.x; vv[1] = u0.z; vv[2] = u1.x; vv[3] = u1.z;
      }
    }
#pragma unroll
    for (int j = 0; j < 4; j++) {
      int s_ = sl + j;
      zt[s_ * CP + (f ^ ((((s_) >> 2) & XM) << 3))] = vv[j];
    }
  }
  __syncthreads();

  int w = tid >> 6;
  int lane = tid & 63;
  int lm = lane & 15, kh = lane >> 4;
  int o0w = (w / 2) * (COUT / 2);
  int col0 = (w % 2) * 64;
  int obBase = o0w >> 4;

  f32x4 acc[MF][NF];
#pragma unroll
  for (int mf = 0; mf < MF; mf++)
#pragma unroll
    for (int nf = 0; nf < NF; nf++) acc[mf][nf] = (f32x4){0.f, 0.f, 0.f, 0.f};

#pragma unroll
  for (int cb = 0; cb < KPAD / 32; cb++) {
    s16x8 a[MF], b[NF];
#pragma unroll
    for (int mf = 0; mf < MF; mf++)
      a[mf] = *reinterpret_cast<const s16x8*>(&wl[((obBase + mf) * (KPAD / 32) + cb) * 512 + lane * 8]);
#pragma unroll
    for (int nf = 0; nf < NF; nf++) {
      int col = col0 + nf * 16 + lm;
      int off = (cb * 32 + kh * 8) ^ (((col >> 2) & XM) << 3);
      b[nf] = *reinterpret_cast<const s16x8*>(&zt[col * CP + off]);
    }
#pragma unroll
    for (int mf = 0; mf < MF; mf++)
#pragma unroll
      for (int nf = 0; nf < NF; nf++)
        acc[mf][nf] = __builtin_amdgcn_mfma_f32_16x16x32_bf16(a[mf], b[nf], acc[mf][nf], 0, 0, 0);
  }

  __syncthreads();
  unsigned short* ot = sh;
#pragma unroll
  for (int mf = 0; mf < MF; mf++)
#pragma unroll
    for (int nf = 0; nf < NF; nf++) {
      int col = col0 + nf * 16 + lm;
#pragma unroll
      for (int rr = 0; rr < 4; rr++) {
        int o = o0w + mf * 16 + kh * 4 + rr;
        ot[o * BNP + col] = f2bf(acc[mf][nf][rr]);
      }
    }
  __syncthreads();
  for (int i = tid * 4; i < COUT * BN; i += 1024) {
    int o = i / BN, col = i - (i / BN) * BN;
    ushort4 rv = *reinterpret_cast<const ushort4*>(&ot[o * BNP + col]);
    ushort4 cv = *reinterpret_cast<const ushort4*>(&cbuf[(((size_t)bl * COUT + o) * NN + n) * TOUT + t0 + col]);
    float m = stL[2 * o], rs = stL[2 * o + 1], bb = brL[o];
    ushort4 ov;
    float v0 = fmaxf((bf2f(cv.x) - m) * rs, 0.f) + bf2f(rv.x) + bb;
    float v1 = fmaxf((bf2f(cv.y) - m) * rs, 0.f) + bf2f(rv.y) + bb;
    float v2 = fmaxf((bf2f(cv.z) - m) * rs, 0.f) + bf2f(rv.z) + bb;
    float v3 = fmaxf((bf2f(cv.w) - m) * rs, 0.f) + bf2f(rv.w) + bb;
    ov.x = f2bf(fmaxf(v0, 0.f));
    ov.y = f2bf(fmaxf(v1, 0.f));
    ov.z = f2bf(fmaxf(v2, 0.f));
    ov.w = f2bf(fmaxf(v3, 0.f));
    *reinterpret_cast<ushort4*>(&out[(((size_t)bl * COUT + o) * NN + n) * TOUT + t0 + col]) = ov;
  }
}

// ---------------- node-mean pool --------------------------------------------
__global__ __launch_bounds__(256) void k_pool(const unsigned short* __restrict__ src,
                                              float* __restrict__ pooled, int b0) {
  constexpr int CP2 = 128, TPZ = 512;
  int t = blockIdx.x * 64 + (threadIdx.x & 63);
  int c = blockIdx.y * 4 + (threadIdx.x >> 6);
  int bl = blockIdx.z;
  const unsigned short* p = src + ((size_t)bl * CP2 + c) * NN * TPZ + t;
  float s = 0.f;
  for (int n = 0; n < NN; n++) s += bf2f(p[(size_t)n * TPZ]);
  pooled[((size_t)(b0 + bl) * TPZ + t) * CP2 + c] = s * (1.f / NN);
}

// ---------------- attention scores ------------------------------------------
__global__ __launch_bounds__(128) void k_attn1(const float* __restrict__ pooled,
                                               const float* __restrict__ w1,
                                               const float* __restrict__ b1,
                                               const float* __restrict__ w2,
                                               const float* __restrict__ b2v,
                                               float* __restrict__ score) {
  __shared__ float w1L[128 * 64];
  __shared__ float w2L[64];
  __shared__ float b1L[64];
  int b = blockIdx.y;
  int t = blockIdx.x * 128 + threadIdx.x;
  int tid = threadIdx.x;
  for (int i = tid; i < 128 * 64; i += 128) w1L[i] = w1[i];
  if (tid < 64) {
    w2L[tid] = w2[tid];
    b1L[tid] = b1[tid];
  }
  __syncthreads();
  float hid[64];
#pragma unroll
  for (int j = 0; j < 64; j++) hid[j] = b1L[j];
  const float* pv = &pooled[((size_t)b * 512 + t) * 128];
  for (int c = 0; c < 128; c++) {
    float xv = pv[c];
#pragma unroll
    for (int j = 0; j < 64; j++) hid[j] += xv * w1L[c * 64 + j];
  }
  float s = b2v[0];
#pragma unroll
  for (int j = 0; j < 64; j++) s += tanhf(hid[j]) * w2L[j];
  score[(size_t)b * 512 + t] = s;
}

// ---------------- softmax over T'=512 per sample ----------------------------
__global__ __launch_bounds__(256) void k_attn2(const float* __restrict__ score,
                                               float* __restrict__ wgt) {
  __shared__ float sc[512];
  __shared__ float red[4];
  int b = blockIdx.x;
  int tid = threadIdx.x;
  for (int t = tid; t < 512; t += 256) sc[t] = score[(size_t)b * 512 + t];
  __syncthreads();
  float mx = -1e30f;
  for (int t = tid; t < 512; t += 256) mx = fmaxf(mx, sc[t]);
  for (int off = 32; off; off >>= 1) mx = fmaxf(mx, __shfl_down(mx, off));
  if ((tid & 63) == 0) red[tid >> 6] = mx;
  __syncthreads();
  mx = fmaxf(fmaxf(red[0], red[1]), fmaxf(red[2], red[3]));
  __syncthreads();
  float sum = 0.f;
  for (int t = tid; t < 512; t += 256) {
    float e = expf(sc[t] - mx);
    sc[t] = e;
    sum += e;
  }
  for (int off = 32; off; off >>= 1) sum += __shfl_down(sum, off);
  if ((tid & 63) == 0) red[tid >> 6] = sum;
  __syncthreads();
  float inv = 1.f / (red[0] + red[1] + red[2] + red[3]);
  for (int t = tid; t < 512; t += 256) wgt[(size_t)b * 512 + t] = sc[t] * inv;
}

// ---------------- weighted feature chunks -----------------------------------
__global__ __launch_bounds__(256) void k_feat2(const float* __restrict__ pooled,
                                               const float* __restrict__ wgt,
                                               float* __restrict__ featb) {
  __shared__ float sh[16][17];
  int b = blockIdx.y;
  int c0 = blockIdx.x * 16;
  int cl = threadIdx.x & 15, tlane = threadIdx.x >> 4;
  float s = 0.f;
  for (int t = tlane; t < 512; t += 16)
    s += pooled[((size_t)b * 512 + t) * 128 + c0 + cl] * wgt[(size_t)b * 512 + t];
  sh[tlane][cl] = s;
  __syncthreads();
  if (threadIdx.x < 16) {
    float a = 0.f;
    for (int q = 0; q < 16; q++) a += sh[q][threadIdx.x];
    featb[(size_t)b * 128 + c0 + threadIdx.x] = a;
  }
}

// ---------------- logits ----------------------------------------------------
__global__ __launch_bounds__(128) void k_logits(const float* __restrict__ featb,
                                                const float* __restrict__ fcw,
                                                const float* __restrict__ fcb,
                                                float* __restrict__ out) {
  __shared__ float fL[128];
  int b = blockIdx.x;
  fL[threadIdx.x] = featb[(size_t)b * 128 + threadIdx.x];
  __syncthreads();
  if (threadIdx.x < 3) {
    float l = fcb[threadIdx.x];
    for (int cc = 0; cc < 128; cc++) l += fL[cc] * fcw[cc * 3 + threadIdx.x];
    out[(size_t)b * 3 + threadIdx.x] = l;
  }
}

// ============================================================================
extern "C" void kernel_launch(void* const* d_in, const int* in_sizes, int n_in,
                              void* d_out, int out_size, void* d_ws, size_t ws_size,
                              hipStream_t stream) {
  (void)in_sizes; (void)n_in; (void)out_size;
  const float* x = (const float*)d_in[0];
  const float* adj = (const float*)d_in[1];
  const float* gw0 = (const float*)d_in[2];
  const float* cw0 = (const float*)d_in[4];
  const float* rw0 = (const float*)d_in[6];
  const float* rb0 = (const float*)d_in[7];
  const float* gw1 = (const float*)d_in[8];
  const float* cw1 = (const float*)d_in[10];
  const float* rw1 = (const float*)d_in[12];
  const float* rb1 = (const float*)d_in[13];
  const float* gw2 = (const float*)d_in[14];
  const float* cw2 = (const float*)d_in[16];
  const float* rw2 = (const float*)d_in[18];
  const float* rb2 = (const float*)d_in[19];
  const float* aw1 = (const float*)d_in[20];
  const float* ab1 = (const float*)d_in[21];
  const float* aw2 = (const float*)d_in[22];
  const float* ab2 = (const float*)d_in[23];
  const float* fcw = (const float*)d_in[24];
  const float* fcb = (const float*)d_in[25];
  float* out = (float*)d_out;
  float* ws = (float*)d_ws;

  // ---- shared ws region (sizes in floats) ----
  float* a_norm = ws;                                                      // 3844
  unsigned short* wk0 = (unsigned short*)(a_norm + 3844);                  // 4608 f
  unsigned short* wk1 = (unsigned short*)(a_norm + 8452);                  // 18432 f
  unsigned short* wk2 = (unsigned short*)(a_norm + 26884);                 // 73728 f
  unsigned short* wg0f = (unsigned short*)(a_norm + 100612);               // 512 f
  unsigned short* wg1f = (unsigned short*)(a_norm + 101124);               // 1024 f
  unsigned short* wg2f = (unsigned short*)(a_norm + 102148);               // 4096 f
  unsigned short* anf = (unsigned short*)(a_norm + 106244);                // 2048 f
  unsigned short* wr0f = (unsigned short*)(a_norm + 108292);               // 512 f
  unsigned short* wr1f = (unsigned short*)(a_norm + 108804);               // 1024 f
  unsigned short* wr2f = (unsigned short*)(a_norm + 109828);               // 4096 f
  float* pooled = a_norm + 113924;                                         // 2097152
  float* scoreb = pooled + 2097152;                                        // 16384
  float* wgtA = scoreb + 16384;                                            // 16384
  float* featb = wgtA + 16384;                                             // 4096
  float* chunk_base = featb + 4096;
  size_t shared_floats = (size_t)(chunk_base - ws);

  const size_t PS_BUF = 2031616;   // bf16 activation buffer (float slots)
  const size_t PS_P1 = 131072;     // wmix stats partials
  const size_t PS_P2 = 65536;      // conv stats partials
  const size_t per_sample = 3 * PS_BUF + PS_P1 + PS_P2 + 512;

  size_t avail = ws_size / sizeof(float);
  long cap = 1;
  if (avail > shared_floats) cap = (long)((avail - shared_floats) / per_sample);
  int Bc = (int)cap;
  if (Bc < 1) Bc = 1;
  if (Bc > 32) Bc = 32;

  // one-time prep: 2 launches total
  k_prep<<<dim3(1), dim3(256), 0, stream>>>(adj, a_norm, out + 96);
  k_wall<<<dim3(576, 10), dim3(256), 0, stream>>>(
      a_norm, anf, cw0, wk0, cw1, wk1, cw2, wk2,
      gw0, wg0f, gw1, wg1f, gw2, wg2f, rw0, wr0f, rw1, wr1f, rw2, wr2f);

  float* sp1 = chunk_base;                        // Bc*131072
  float* sp2 = sp1 + (size_t)Bc * PS_P1;          // Bc*65536
  float* stY = sp2 + (size_t)Bc * PS_P2;          // Bc*256
  float* stC = stY + (size_t)Bc * 256;            // Bc*256
  float* B1 = stC + (size_t)Bc * 256;
  float* B2 = B1 + (size_t)Bc * PS_BUF;
  float* B3 = B2 + (size_t)Bc * PS_BUF;

  for (int b0 = 0; b0 < 32; b0 += Bc) {
    int bc = (32 - b0 < Bc) ? (32 - b0) : Bc;
    unsigned short* B1u = (unsigned short*)B1;
    unsigned short* B2u = (unsigned short*)B2;
    unsigned short* B3u = (unsigned short*)B3;

    // ---- block 0: 5 -> 32, T 1024, stride 1 ----
    k_xcast<<<dim3(4, NN, bc), dim3(256), 0, stream>>>(x, B1u, b0);
    k_spatmma<5, 1024><<<dim3(4, 5, bc), dim3(256), 0, stream>>>(B1u, anf, B2u);
    k_wmixmma<5, 32, 1024><<<dim3(248, bc), dim3(256), 0, stream>>>(B2u, wg0f, B3u, sp1);
    k_statsR<<<dim3(32, bc), dim3(256), 0, stream>>>(sp1, stY, 248, 1.f / 63488.f);
    k_convmma<32, 1024, 1, 256><<<dim3(4, NN, bc), dim3(512), 0, stream>>>(B3u, wk0, stY, B2u, sp2);
    k_statsR<<<dim3(32, bc), dim3(256), 0, stream>>>(sp2, stC, 248, 1.f / 63488.f);
    k_postmma<5, 32, 1024, 1><<<dim3(8, NN, bc), dim3(256), 0, stream>>>(
        B2u, stC, B1u, wr0f, rb0, B3u);  // A -> B3u

    // ---- block 1: 32 -> 64, T 1024->512, stride 2; in = A (B3u) ----
    k_spatmma<32, 1024><<<dim3(4, 32, bc), dim3(256), 0, stream>>>(B3u, anf, B1u);
    k_wmixmma<32, 64, 1024><<<dim3(248, bc), dim3(256), 0, stream>>>(B1u, wg1f, B2u, sp1);
    k_statsR<<<dim3(64, bc), dim3(256), 0, stream>>>(sp1, stY, 248, 1.f / 63488.f);
    k_convmma<64, 1024, 2, 128><<<dim3(4, NN, bc), dim3(512), 0, stream>>>(B2u, wk1, stY, B1u, sp2);
    k_statsR<<<dim3(64, bc), dim3(256), 0, stream>>>(sp2, stC, 248, 1.f / 31744.f);
    k_postmma<32, 64, 512, 2><<<dim3(4, NN, bc), dim3(256), 0, stream>>>(
        B1u, stC, B3u, wr1f, rb1, B2u);  // D -> B2u

    // ---- block 2: 64 -> 128, T 512, stride 1; in = D (B2u) ----
    k_spatmma<64, 512><<<dim3(2, 64, bc), dim3(256), 0, stream>>>(B2u, anf, B3u);
    k_wmixmma<64, 128, 512><<<dim3(248, bc), dim3(256), 0, stream>>>(B3u, wg2f, B1u, sp1);
    k_statsR<<<dim3(128, bc), dim3(256), 0, stream>>>(sp1, stY, 248, 1.f / 31744.f);
    k_convmma<128, 512, 1, 128><<<dim3(4, NN, bc), dim3(512), 0, stream>>>(B1u, wk2, stY, B3u, sp2);
    k_statsR<<<dim3(128, bc), dim3(256), 0, stream>>>(sp2, stC, 248, 1.f / 31744.f);
    k_postmma<64, 128, 512, 1><<<dim3(4, NN, bc), dim3(256), 0, stream>>>(
        B3u, stC, B2u, wr2f, rb2, B1u);  // OUT -> B1u

    k_pool<<<dim3(8, 32, bc), dim3(256), 0, stream>>>(B1u, pooled, b0);
  }

  // ---- head: full batch at once (fp32) ----
  k_attn1<<<dim3(4, 32), dim3(128), 0, stream>>>(pooled, aw1, ab1, aw2, ab2, scoreb);
  k_attn2<<<dim3(32), dim3(256), 0, stream>>>(scoreb, wgtA);
  k_feat2<<<dim3(8, 32), dim3(256), 0, stream>>>(pooled, wgtA, featb);
  k_logits<<<dim3(32), dim3(128), 0, stream>>>(featb, fcw, fcb, out);
}